// Round 8
// baseline (980.797 us; speedup 1.0000x reference)
//
#include <hip/hip_runtime.h>
#include <cfloat>

// E8 codebook quantize: per row of X[N][8]
//   neg mask, parity -> X_part = |X| with coord0 sign-fixed
//   scores = 2*dot - norm, argmax (first-max), vals/idx via sign-unflip + gather
//
// Scoring order (R8 hypothesis): SIMD horizontal-reduction semantics —
// separately rounded products, 128-bit fold q_i = p_i + p_{i+4}, then
// adjacent tree:  d = (q0+q1) + (q2+q3).
// This is the numpy-einsum SSE sum_of_products / LLVM autovectorized-K8
// reduction pattern — the remaining plausible golden chain after R1-R7
// excluded seq-FMA, seq-mul-add, adjacent-pairwise, round-once-exact, f64.
// #pragma clang fp contract(off) forces real v_mul_f32 + v_add_f32.
//
// Output d_out (float*): vals [N*8] then real_idx [N] (int stored as float).
// allcombo/idx_map are int32-canonicalized on device (established R1-R3).

__global__ __launch_bounds__(256, 4)
void e8_quant_kernel(const float* __restrict__ X,
                     const float* __restrict__ grid_part,   // [P*8] f32
                     const float* __restrict__ grid_norm,   // [P]   f32
                     const int*   __restrict__ allcombo,    // [128*P] int32
                     const int*   __restrict__ idx_map,     // [256] int32
                     float* __restrict__ out,               // [N*8 + N]
                     int N, int P)
{
    #pragma clang fp contract(off)

    extern __shared__ float smem[];
    float* s_grid = smem;                       // P*8 floats
    float* s_n    = smem + (size_t)P * 8;       // P floats (full norm)
    int*   s_imap = (int*)(s_n + P);            // 256 ints

    for (int i = threadIdx.x; i < P * 8; i += blockDim.x) s_grid[i] = grid_part[i];
    for (int i = threadIdx.x; i < P;     i += blockDim.x) s_n[i]    = grid_norm[i];
    for (int i = threadIdx.x; i < 256;   i += blockDim.x) s_imap[i] = idx_map[i];
    __syncthreads();

    int row = blockIdx.x * blockDim.x + threadIdx.x;
    if (row >= N) return;

    const float4* xr = reinterpret_cast<const float4*>(X + (size_t)row * 8);
    float4 xa = xr[0];
    float4 xb = xr[1];
    float x[8] = { xa.x, xa.y, xa.z, xa.w, xb.x, xb.y, xb.z, xb.w };

    // neg mask + parity
    unsigned nm = 0u;
    #pragma unroll
    for (int c = 0; c < 8; ++c) nm |= (x[c] < 0.0f) ? (1u << c) : 0u;
    unsigned odd = __popc(nm) & 1u;

    // X_part = |x|, coord0 negated when parity odd (exact sign ops)
    float xp[8];
    #pragma unroll
    for (int c = 0; c < 8; ++c) xp[c] = fabsf(x[c]);
    if (odd) xp[0] = -xp[0];

    // argmax over codebook: SIMD-horizontal fold+adjacent tree, first-max via >
    float best = -FLT_MAX;
    int   bidx = 0;
    #pragma unroll 2
    for (int p = 0; p < P; ++p) {
        const float4* g4 = reinterpret_cast<const float4*>(s_grid + (size_t)p * 8);
        float4 ga = g4[0];
        float4 gb = g4[1];
        // separately-rounded products (contract off => real v_mul_f32)
        float p0 = xp[0] * ga.x;
        float p1 = xp[1] * ga.y;
        float p2 = xp[2] * ga.z;
        float p3 = xp[3] * ga.w;
        float p4 = xp[4] * gb.x;
        float p5 = xp[5] * gb.y;
        float p6 = xp[6] * gb.z;
        float p7 = xp[7] * gb.w;
        // 128-bit fold: q_i = p_i + p_{i+4}
        float q0 = p0 + p4;
        float q1 = p1 + p5;
        float q2 = p2 + p6;
        float q3 = p3 + p7;
        // adjacent merge
        float t0 = q0 + q1;
        float t1 = q2 + q3;
        float d  = t0 + t1;
        float s  = 2.0f * d - s_n[p];       // 2d exact, single rounding
        bool gt = (s > best);
        best = gt ? s : best;
        bidx = gt ? p : bidx;
    }

    // packed sign bits: bit c = neg[c] for c>=1, bit0 = neg0 ^ parity
    unsigned packed = (nm & 0xFEu) | ((nm ^ odd) & 1u);

    // vals = grid_part[best] * mask (exact sign flips)
    const float* g = s_grid + (size_t)bidx * 8;
    float v[8];
    #pragma unroll
    for (int c = 0; c < 8; ++c) {
        float gv = g[c];
        v[c] = ((packed >> c) & 1u) ? -gv : gv;
    }
    float4* orow = reinterpret_cast<float4*>(out + (size_t)row * 8);
    float4 o0 = { v[0], v[1], v[2], v[3] };
    float4 o1 = { v[4], v[5], v[6], v[7] };
    orow[0] = o0;
    orow[1] = o1;

    // real_idx = allcombo[idx_map[packed]][best]
    int crow = s_imap[packed];
    int idxv = allcombo[(size_t)crow * P + bidx];
    out[(size_t)N * 8 + row] = (float)idxv;
}

extern "C" void kernel_launch(void* const* d_in, const int* in_sizes, int n_in,
                              void* d_out, int out_size, void* d_ws, size_t ws_size,
                              hipStream_t stream) {
    const float* X        = (const float*)d_in[0];
    const float* gridpart = (const float*)d_in[1];
    const float* gridnorm = (const float*)d_in[2];
    // d_in[3] = int_map (2^c) — hardcoded as bit shifts
    const int*   allcombo = (const int*)d_in[4];
    const int*   idxmap   = (const int*)d_in[5];
    float* out = (float*)d_out;

    int N = in_sizes[0] / 8;
    int P = in_sizes[2];

    int block = 256;
    int grid  = (N + block - 1) / block;
    size_t lds_bytes = (size_t)P * 9 * sizeof(float) + 256 * sizeof(int);

    hipLaunchKernelGGL(e8_quant_kernel, dim3(grid), dim3(block), lds_bytes, stream,
                       X, gridpart, gridnorm, allcombo, idxmap, out, N, P);
}

// Round 9
// 431.437 us; speedup vs baseline: 2.2733x; 2.2733x over previous
//
#include <hip/hip_runtime.h>
#include <cfloat>

// E8 codebook quantize: per row of X[N][8]
//   neg mask, parity -> X_part = |X| with coord0 sign-fixed
//   scores = 2*dot - norm, argmax (first-max), vals/idx via sign-unflip + gather
//
// Scoring order (VERIFIED EXACT in R8, absmax=0): SIMD horizontal-reduction —
// separately rounded products, 128-bit fold q_i = p_i + p_{i+4}, adjacent tree
// d = (q0+q1)+(q2+q3), then s = fl(2d - n) (2d exact => fmaf(2,d,-n) is
// bit-identical to fl(fl(2d)-n)). DO NOT change this chain.
//
// R9 perf restructure (semantics untouched):
//   - codebook reads are wave-uniform (p is the loop var) -> read directly
//     from global; hipcc scalarizes to s_load through the constant cache,
//     off the VALU/LDS pipes. No LDS at all, no __syncthreads, no LDS
//     address VALU overhead. 96 KB codebook is L2-resident.
//   - #pragma unroll 4 so s_loads for later iterations issue early.
//   - VALU floor ~200 us (20 ops x P~2990 x 4096 waves); prior LDS version
//     measured 990 us @ VALUBusy 44%.
//
// Output d_out (float*): vals [N*8] then real_idx [N] (int stored as float).
// allcombo/idx_map are int32-canonicalized on device (established R1-R3).

__global__ __launch_bounds__(256, 4)
void e8_quant_kernel(const float* __restrict__ X,
                     const float* __restrict__ grid_part,   // [P*8] f32
                     const float* __restrict__ grid_norm,   // [P]   f32
                     const int*   __restrict__ allcombo,    // [128*P] int32
                     const int*   __restrict__ idx_map,     // [256] int32
                     float* __restrict__ out,               // [N*8 + N]
                     int N, int P)
{
    #pragma clang fp contract(off)

    int row = blockIdx.x * blockDim.x + threadIdx.x;
    if (row >= N) return;

    const float4* xr = reinterpret_cast<const float4*>(X + (size_t)row * 8);
    float4 xa = xr[0];
    float4 xb = xr[1];
    float x[8] = { xa.x, xa.y, xa.z, xa.w, xb.x, xb.y, xb.z, xb.w };

    // neg mask + parity
    unsigned nm = 0u;
    #pragma unroll
    for (int c = 0; c < 8; ++c) nm |= (x[c] < 0.0f) ? (1u << c) : 0u;
    unsigned odd = __popc(nm) & 1u;

    // X_part = |x|, coord0 negated when parity odd (exact sign ops)
    float xp0 = fabsf(x[0]);
    xp0 = odd ? -xp0 : xp0;
    float xp1 = fabsf(x[1]);
    float xp2 = fabsf(x[2]);
    float xp3 = fabsf(x[3]);
    float xp4 = fabsf(x[4]);
    float xp5 = fabsf(x[5]);
    float xp6 = fabsf(x[6]);
    float xp7 = fabsf(x[7]);

    // argmax over codebook: golden fold+adjacent tree, first-max via strict >
    // codebook loads are wave-uniform -> scalar (s_load) path, off VALU/LDS.
    const float4* gp4 = reinterpret_cast<const float4*>(grid_part);
    float best = -FLT_MAX;
    int   bidx = 0;
    #pragma unroll 4
    for (int p = 0; p < P; ++p) {
        float4 ga = gp4[2 * p];
        float4 gb = gp4[2 * p + 1];
        float nrm = grid_norm[p];
        // separately-rounded products (contract off => real v_mul_f32)
        float p0 = xp0 * ga.x;
        float p1 = xp1 * ga.y;
        float p2 = xp2 * ga.z;
        float p3 = xp3 * ga.w;
        float p4 = xp4 * gb.x;
        float p5 = xp5 * gb.y;
        float p6 = xp6 * gb.z;
        float p7 = xp7 * gb.w;
        // 128-bit fold: q_i = p_i + p_{i+4}
        float q0 = p0 + p4;
        float q1 = p1 + p5;
        float q2 = p2 + p6;
        float q3 = p3 + p7;
        // adjacent merge
        float t0 = q0 + q1;
        float t1 = q2 + q3;
        float d  = t0 + t1;
        // s = fl(2d - n): 2d exact, single rounding == fl(fl(2d)-n)
        float s  = fmaf(2.0f, d, -nrm);
        bool gt = (s > best);
        best = gt ? s : best;
        bidx = gt ? p : bidx;
    }

    // packed sign bits: bit c = neg[c] for c>=1, bit0 = neg0 ^ parity
    unsigned packed = (nm & 0xFEu) | ((nm ^ odd) & 1u);

    // vals = grid_part[best] * mask (exact sign flips)
    const float* g = grid_part + (size_t)bidx * 8;
    float v[8];
    #pragma unroll
    for (int c = 0; c < 8; ++c) {
        float gv = g[c];
        v[c] = ((packed >> c) & 1u) ? -gv : gv;
    }
    float4* orow = reinterpret_cast<float4*>(out + (size_t)row * 8);
    float4 o0 = { v[0], v[1], v[2], v[3] };
    float4 o1 = { v[4], v[5], v[6], v[7] };
    orow[0] = o0;
    orow[1] = o1;

    // real_idx = allcombo[idx_map[packed]][best]
    int crow = idx_map[packed];
    int idxv = allcombo[(size_t)crow * P + bidx];
    out[(size_t)N * 8 + row] = (float)idxv;
}

extern "C" void kernel_launch(void* const* d_in, const int* in_sizes, int n_in,
                              void* d_out, int out_size, void* d_ws, size_t ws_size,
                              hipStream_t stream) {
    const float* X        = (const float*)d_in[0];
    const float* gridpart = (const float*)d_in[1];
    const float* gridnorm = (const float*)d_in[2];
    // d_in[3] = int_map (2^c) — hardcoded as bit shifts
    const int*   allcombo = (const int*)d_in[4];
    const int*   idxmap   = (const int*)d_in[5];
    float* out = (float*)d_out;

    int N = in_sizes[0] / 8;
    int P = in_sizes[2];

    int block = 256;
    int grid  = (N + block - 1) / block;

    hipLaunchKernelGGL(e8_quant_kernel, dim3(grid), dim3(block), 0, stream,
                       X, gridpart, gridnorm, allcombo, idxmap, out, N, P);
}